// Round 15
// baseline (434.521 us; speedup 1.0000x reference)
//
#include <hip/hip_runtime.h>
#include <cstdint>
#include <cstddef>

#define DIM 2048
#define NHEADS 16
#define HD 128
#define BATCH 4
#define SEQ 2048
#define MROWS (BATCH*SEQ)   // 8192
#define NT 32               // K tiles (2048/64)
#define TSZ (256*64)        // one LDS tile in shorts (32 KiB)

typedef __attribute__((ext_vector_type(4))) float  f32x4;
typedef __attribute__((ext_vector_type(4))) float  float4v;
typedef __attribute__((ext_vector_type(8))) short  short8;
typedef __attribute__((ext_vector_type(4))) short  short4v;
typedef __attribute__((ext_vector_type(4))) unsigned uint4v;
typedef __attribute__((ext_vector_type(8))) __bf16 bf16x8;

// Q is pre-scaled by (1/sqrt(128)) * log2(e) so flash softmax runs in exp2 domain.
#define QSCALE 0.1275173772f

__device__ __forceinline__ unsigned f2bfbits(float f) {
  unsigned u = __builtin_bit_cast(unsigned, f);
  return (u + 0x7FFFu + ((u >> 16) & 1u)) >> 16;
}
__device__ __forceinline__ short f2bf(float f) { return (short)f2bfbits(f); }
__device__ __forceinline__ float bf2f(short s) {
  unsigned u = ((unsigned)(unsigned short)s) << 16;
  return __builtin_bit_cast(float, u);
}
__device__ __forceinline__ unsigned cvtpk_bf16(float lo, float hi) {
  unsigned r;
  asm("v_cvt_pk_bf16_f32 %0, %1, %2" : "=v"(r) : "v"(lo), "v"(hi));
  return r;
}
__device__ __forceinline__ f32x4 mfma16(short8 a, short8 b, f32x4 c) {
  return __builtin_amdgcn_mfma_f32_16x16x32_bf16(
      __builtin_bit_cast(bf16x8, a), __builtin_bit_cast(bf16x8, b), c, 0, 0, 0);
}
// async global->LDS, 16B per lane. LDS dest is wave-uniform base + lane*16.
__device__ __forceinline__ void gload16(const short* g, short* l) {
  __builtin_amdgcn_global_load_lds(
      (const __attribute__((address_space(1))) unsigned int*)g,
      (__attribute__((address_space(3))) unsigned int*)l, 16, 0, 0);
}

// ---------------------------------------------------------------- prep: x -> bf16
__global__ __launch_bounds__(256) void k_convert_x(const float* __restrict__ x,
                                                   short* __restrict__ xb) {
  size_t i = ((size_t)blockIdx.x * 256 + threadIdx.x) * 8;
  float4v a = *(const float4v*)(x + i);
  float4v b = *(const float4v*)(x + i + 4);
  short8 o;
  o[0] = f2bf(a[0]); o[1] = f2bf(a[1]); o[2] = f2bf(a[2]); o[3] = f2bf(a[3]);
  o[4] = f2bf(b[0]); o[5] = f2bf(b[1]); o[6] = f2bf(b[2]); o[7] = f2bf(b[3]);
  *(short8*)(xb + i) = o;
}

// ------------------------------------------------- prep: W [K][N] f32 -> Wt [N][K] bf16
__global__ __launch_bounds__(256) void k_transpose_w(
    const float* __restrict__ w0, const float* __restrict__ w1,
    const float* __restrict__ w2, const float* __restrict__ w3,
    short* __restrict__ o0, short* __restrict__ o1,
    short* __restrict__ o2, short* __restrict__ o3) {
  const float* w; short* o;
  switch (blockIdx.z) {
    case 0: w = w0; o = o0; break;
    case 1: w = w1; o = o1; break;
    case 2: w = w2; o = o2; break;
    default: w = w3; o = o3; break;
  }
  __shared__ float tile[32][33];
  int tx = threadIdx.x, ty = threadIdx.y;          // 32 x 8
  int kb = blockIdx.y * 32, nb = blockIdx.x * 32;
#pragma unroll
  for (int i = 0; i < 4; ++i)
    tile[ty + 8 * i][tx] = w[(size_t)(kb + ty + 8 * i) * DIM + nb + tx];
  __syncthreads();
#pragma unroll
  for (int i = 0; i < 4; ++i)
    o[(size_t)(nb + ty + 8 * i) * DIM + kb + tx] = f2bf(tile[tx][ty + 8 * i]);
}

// ---------------------------------------------------------------- 256x256 8-wave GEMM
// m201-style 4-phase K-tile schedule, 5 barriers/tile (top + 4 pre-MFMA).
// 512 thr = 8 waves (2M x 4N), wave tile 128x64, acc[8][4].
// Per K-tile t (buf c=t&1):
//   top: [vmcnt from prev tile] barrier (tile t staged everywhere)
//   ph1: read av(ih0,ks0)+bv0(ks0); issue stage A.H1(t+1)->c^1; barrier; 16 MFMA
//   ph2: read av(ih0,ks1)+bv1(ks1); issue stage A.H2(t+1);      barrier; 16 MFMA
//   ph3: read av(ih1,ks0); barrier; issue stage B.H1(t+2)->c;   16 MFMA (bv0 regs)
//        (safe: passing ph3's barrier proves all waves' ph2 MFMA consumed bv1,
//         so all B-reads of tile t are complete before the B-restage lands)
//   ph4: read av(ih1,ks1); barrier; issue stage B.H2(t+2);      16 MFMA (bv1 regs)
//        s_waitcnt vmcnt(4)  (A(t+1) landed; exactly B(t+2)'s 4 loads in flight)
// 24 ds_read_b128/wave/tile (reuse-minimal); reads always issued pre-barrier so
// their latency is absorbed by the rendezvous; counted waits never drain mid-loop.
// LDS XOR swizzle both-sides: LDS[r][s] = G[r][s ^ (r&7)], read slot ((ks<<2)|gi)^(li&7).
// MODE 0: fused QKV + RoPE (grid 768 flat, XCD remap); MODE 1: out proj (grid 256).
template<int MODE>
__global__ __launch_bounds__(512, 1) void k_gemm256(const short* __restrict__ A,
                                                    const short* __restrict__ BtAll,
                                                    const float* __restrict__ cosg,
                                                    const float* __restrict__ sing,
                                                    short* __restrict__ Qp,
                                                    short* __restrict__ Kp,
                                                    short* __restrict__ Vp,
                                                    float* __restrict__ Of) {
  __shared__ short As[2 * TSZ];
  __shared__ short Bs[2 * TSZ];
  const int t = threadIdx.x;
  const int lane = t & 63, wid = t >> 6;          // 8 waves
  const int wm = wid >> 2, wn = wid & 3;          // 2 x 4
  const int gi = lane >> 4, li = lane & 15;
  const int id = blockIdx.x;
  const int wg = MODE == 0 ? ((id & 7) * 96 + (id >> 3)) : ((id & 7) * 32 + (id >> 3));
  const int bm = wg & 31, bn = wg >> 5;
  const int m0 = bm * 256;
  const int which = MODE == 0 ? (bn >> 3) : 0;
  const int n0 = MODE == 0 ? ((bn & 7) * 256) : (bn * 256);
  const short* Bg = BtAll + (size_t)which * DIM * DIM;
  const short* Ag = A;

  const int lrow = lane >> 3;                     // 0..7
  const int lcol = ((lane & 7) ^ lrow) * 8;       // pre-swizzled source col (shorts)
  const int hh = wn >> 1, hf = wn & 1;            // MODE 0 col remap

  // wave's local output col for fragment j (0..3); MODE 0 keeps rope pair in-wave.
  auto bcol = [&](int j) {
    if (MODE == 0) return hh * 128 + (j >> 1) * 64 + hf * 32 + (j & 1) * 16;
    return wn * 64 + j * 16;
  };

  auto stageA = [&](int h, int tile) {
    const int kk0 = tile * 64;
    short* d = As + (tile & 1) * TSZ;
#pragma unroll
    for (int u = 0; u < 2; ++u) {
      int rb = h * 128 + u * 64 + wid * 8;
      gload16(Ag + (size_t)(m0 + rb + lrow) * DIM + kk0 + lcol, d + rb * 64);
    }
  };
  auto stageB = [&](int h, int tile) {
    const int kk0 = tile * 64;
    short* d = Bs + (tile & 1) * TSZ;
#pragma unroll
    for (int u = 0; u < 2; ++u) {
      int rb = h * 128 + u * 64 + wid * 8;
      gload16(Bg + (size_t)(n0 + rb + lrow) * DIM + kk0 + lcol, d + rb * 64);
    }
  };

  f32x4 acc[8][4];
#pragma unroll
  for (int i = 0; i < 8; ++i)
#pragma unroll
    for (int j = 0; j < 4; ++j) acc[i][j] = (f32x4){0.f, 0.f, 0.f, 0.f};

#define READ_AV(IH, KS)                                                           \
  { const int sw = ((((KS) << 2) | gi) ^ (li & 7)) * 8;                           \
    _Pragma("unroll")                                                             \
    for (int i = 0; i < 4; ++i)                                                   \
      av[i] = *(const short8*)&Ab[(wm * 128 + ((IH) * 4 + i) * 16 + li) * 64 + sw]; }
#define READ_BV(DST, KS)                                                          \
  { const int sw = ((((KS) << 2) | gi) ^ (li & 7)) * 8;                           \
    _Pragma("unroll")                                                             \
    for (int j = 0; j < 4; ++j)                                                   \
      DST[j] = *(const short8*)&Bb[(bcol(j) + li) * 64 + sw]; }
#define MFMA_BLK(IH, BV)                                                          \
  __builtin_amdgcn_s_setprio(1);                                                  \
  _Pragma("unroll")                                                               \
  for (int i = 0; i < 4; ++i)                                                     \
    _Pragma("unroll")                                                             \
    for (int j = 0; j < 4; ++j)                                                   \
      acc[(IH) * 4 + i][j] = mfma16(av[i], BV[j], acc[(IH) * 4 + i][j]);          \
  __builtin_amdgcn_s_setprio(0);

  // prologue (steady-state issue order: B(t) two tiles early, A(t) one early)
  stageB(0, 0); stageB(1, 0);
  stageA(0, 0); stageA(1, 0);
  stageB(0, 1); stageB(1, 1);
  asm volatile("s_waitcnt vmcnt(4)" ::: "memory");
  __builtin_amdgcn_s_barrier();

  for (int tt = 0; tt < NT; ++tt) {
    const short* Ab = As + (tt & 1) * TSZ;
    const short* Bb = Bs + (tt & 1) * TSZ;
    short8 av[4], bv0[4], bv1[4];

    // ph1: ih0 x ks0
    READ_AV(0, 0)
    READ_BV(bv0, 0)
    if (tt + 1 < NT) stageA(0, tt + 1);
    __builtin_amdgcn_s_barrier();
    MFMA_BLK(0, bv0)

    // ph2: ih0 x ks1
    READ_AV(0, 1)
    READ_BV(bv1, 1)
    if (tt + 1 < NT) stageA(1, tt + 1);
    __builtin_amdgcn_s_barrier();
    MFMA_BLK(0, bv1)

    // ph3: ih1 x ks0 (bv0 held in regs; B of tile t fully consumed once all
    // waves pass this barrier -> restage B.H1(t+2) into current buffer)
    READ_AV(1, 0)
    __builtin_amdgcn_s_barrier();
    if (tt + 2 < NT) stageB(0, tt + 2);
    MFMA_BLK(1, bv0)

    // ph4: ih1 x ks1
    READ_AV(1, 1)
    __builtin_amdgcn_s_barrier();
    if (tt + 2 < NT) stageB(1, tt + 2);
    MFMA_BLK(1, bv1)
    if (tt + 2 < NT) asm volatile("s_waitcnt vmcnt(4)" ::: "memory");
    else             asm volatile("s_waitcnt vmcnt(0)" ::: "memory");
    __builtin_amdgcn_s_barrier();                 // tile t+1 ready for all waves
  }
#undef READ_AV
#undef READ_BV
#undef MFMA_BLK

  // ---------------- epilogue ----------------
  if (MODE == 1) {
#pragma unroll
    for (int i = 0; i < 8; ++i)
#pragma unroll
      for (int j = 0; j < 4; ++j)
#pragma unroll
        for (int r = 0; r < 4; ++r) {
          int gm = m0 + wm * 128 + i * 16 + gi * 4 + r;
          int gn = n0 + wn * 64 + j * 16 + li;
          Of[(size_t)gm * DIM + gn] = acc[i][j][r];
        }
    return;
  }
  const int h = 2 * (bn & 7) + hh;
  if (which == 2) {                               // V -> (B,H,D,S)
#pragma unroll
    for (int i = 0; i < 8; ++i)
#pragma unroll
      for (int j = 0; j < 4; ++j) {
        int gm0 = m0 + wm * 128 + i * 16 + gi * 4;
        int b = gm0 >> 11, s0 = gm0 & 2047;
        int d = (j >> 1) * 64 + hf * 32 + (j & 1) * 16 + li;
        short4v pk;
#pragma unroll
        for (int r = 0; r < 4; ++r) pk[r] = f2bf(acc[i][j][r]);
        *(short4v*)&Vp[((size_t)(b * NHEADS + h) * HD + d) * SEQ + s0] = pk;
      }
  } else {                                        // Q or K: rope + store (B,H,S,D)
    short* O = which ? Kp : Qp;
    const float qs = which ? 1.0f : QSCALE;
#pragma unroll
    for (int i = 0; i < 8; ++i)
#pragma unroll
      for (int j = 0; j < 2; ++j) {
        int dlo = hf * 32 + j * 16 + li;          // in [0,64)
#pragma unroll
        for (int r = 0; r < 4; ++r) {
          int gm = m0 + wm * 128 + i * 16 + gi * 4 + r;
          int b = gm >> 11, s = gm & 2047;
          float c = cosg[s * 64 + dlo], sn = sing[s * 64 + dlo];
          float a = acc[i][j][r], bb = acc[i][j + 2][r];
          size_t base = ((size_t)(b * NHEADS + h) * SEQ + s) * HD;
          O[base + dlo]      = f2bf((a * c - bb * sn) * qs);
          O[base + dlo + 64] = f2bf((bb * c + a * sn) * qs);
        }
      }
  }
}

// ---------------------------------------------------------------- causal flash attention
// Q (QSCALE'd, roped), K (roped): (B,H,S,D) bf16; V: (B,H,D,S) bf16; O: (B,S,H*D) bf16.
// 8 waves x 16 q-rows = 128 q-rows per block; each staged K/V tile feeds all 8 waves.
// Staging via gload_lds(16B) into linear LDS, XOR-swizzled both sides.
// Double-buffered, counted vmcnt(4). Grid 1024 with XCD bh-affinity + LPT.
__global__ __launch_bounds__(512) void k_flash(const short* __restrict__ Qg,
                                               const short* __restrict__ Kg,
                                               const short* __restrict__ Vg,
                                               short* __restrict__ Og) {
  __shared__ short Kl[2 * 64 * 128];
  __shared__ short Vl[2 * 128 * 64];
  const int t = threadIdx.x, lane = t & 63, wid = t >> 6;   // 8 waves
  const int gi = lane >> 4, li = lane & 15;
  const int id = blockIdx.x;
  const int ip = 15 - (id >> 6);                  // q-tile (128 rows), heavy-first
  const int bh = (id & 7) * 8 + ((id >> 3) & 7);  // XCD bh-affinity
  const int q0 = ip * 128;
  const short* Qb = Qg + (size_t)bh * SEQ * HD;
  const short* Kb = Kg + (size_t)bh * SEQ * HD;
  const short* Vb = Vg + (size_t)bh * HD * SEQ;
  const int mrow = q0 + wid * 16 + li;            // this lane's q row
  const int nt = 2 * ip + 2;

  short8 qb[4];
#pragma unroll
  for (int kk = 0; kk < 4; ++kk)
    qb[kk] = *(const short8*)(Qb + (size_t)mrow * HD + kk * 32 + 8 * gi);

  f32x4 o[8];
#pragma unroll
  for (int d = 0; d < 8; ++d) o[d] = (f32x4){0.f, 0.f, 0.f, 0.f};
  float mx = -1e30f, lsum = 0.f;
  const int srcA = li | ((lane & 16) << 1);       // (m, 2*(g&1))
  const int srcB = srcA + 16;
  const bool hig = (lane & 32) != 0;

#define FSTAGE(tt, buf)                                                           \
  {                                                                               \
    const int kk0 = (tt) * 64;                                                    \
    short* kl = Kl + (buf) * 8192;                                                \
    short* vl = Vl + (buf) * 8192;                                                \
    _Pragma("unroll")                                                             \
    for (int u = 0; u < 2; ++u) {                                                 \
      int w = wid * 2 + u;                                                        \
      { int row = w * 4 + (lane >> 4); int sl = (lane & 15) ^ (row & 15);         \
        gload16(Kb + (size_t)(kk0 + row) * HD + sl * 8, kl + w * 512); }          \
      { int row = w * 8 + (lane >> 3); int sl = (lane & 7) ^ (row & 7);           \
        gload16(Vb + (size_t)row * SEQ + kk0 + sl * 8, vl + w * 512); }           \
    }                                                                             \
  }

  FSTAGE(0, 0)

  for (int tt = 0; tt < nt; ++tt) {
    const int k0 = tt * 64;
    if (tt + 1 < nt) {
      FSTAGE(tt + 1, (tt + 1) & 1)
      asm volatile("s_waitcnt vmcnt(4)" ::: "memory");
    } else {
      asm volatile("s_waitcnt vmcnt(0)" ::: "memory");
    }
    __builtin_amdgcn_s_barrier();                 // tile tt staged everywhere
    const short* Kc = Kl + (tt & 1) * 8192;
    const short* Vc = Vl + (tt & 1) * 8192;

    f32x4 sacc[4];
#pragma unroll
    for (int af = 0; af < 4; ++af) sacc[af] = (f32x4){0.f, 0.f, 0.f, 0.f};
    __builtin_amdgcn_s_setprio(1);
#pragma unroll
    for (int kk = 0; kk < 4; ++kk)
#pragma unroll
      for (int af = 0; af < 4; ++af) {
        short8 kf = *(const short8*)&Kc[(16 * af + li) * 128 + (((kk << 2) | gi) ^ li) * 8];
        sacc[af] = mfma16(kf, qb[kk], sacc[af]);
      }
    __builtin_amdgcn_s_setprio(0);

    float p[4][4];
    float pmax = -1e30f;
    const bool mask = (k0 + 63 > mrow);
#pragma unroll
    for (int af = 0; af < 4; ++af)
#pragma unroll
      for (int r = 0; r < 4; ++r) {
        float v = sacc[af][r];                    // already scaled (Q pre-scale)
        if (mask && (k0 + 16 * af + 4 * gi + r > mrow)) v = -1e30f;
        p[af][r] = v;
        pmax = fmaxf(pmax, v);
      }
    pmax = fmaxf(pmax, __shfl_xor(pmax, 16));
    pmax = fmaxf(pmax, __shfl_xor(pmax, 32));
    if (!__all(pmax <= mx + 11.54f)) {            // defer-max: rescale only on real growth
      float mnew = fmaxf(mx, pmax);
      float alpha = __builtin_amdgcn_exp2f(mx - mnew);
      lsum *= alpha;
      mx = mnew;
#pragma unroll
      for (int d = 0; d < 8; ++d) o[d] *= alpha;
    }
    float psum = 0.f;
#pragma unroll
    for (int af = 0; af < 4; ++af)
#pragma unroll
      for (int r = 0; r < 4; ++r) {
        float e = __builtin_amdgcn_exp2f(p[af][r] - mx);
        p[af][r] = e;
        psum += e;
      }
    psum += __shfl_xor(psum, 16);
    psum += __shfl_xor(psum, 32);
    lsum += psum;

    unsigned plo[4], phi[4];
#pragma unroll
    for (int af = 0; af < 4; ++af) {
      plo[af] = cvtpk_bf16(p[af][0], p[af][1]);
      phi[af] = cvtpk_bf16(p[af][2], p[af][3]);
    }
#pragma unroll
    for (int kk2 = 0; kk2 < 2; ++kk2) {
      unsigned aAlo = (unsigned)__shfl((int)plo[2 * kk2], srcA);
      unsigned aAhi = (unsigned)__shfl((int)phi[2 * kk2], srcA);
      unsigned aBlo = (unsigned)__shfl((int)plo[2 * kk2 + 1], srcA);
      unsigned aBhi = (unsigned)__shfl((int)phi[2 * kk2 + 1], srcA);
      unsigned bAlo = (unsigned)__shfl((int)plo[2 * kk2], srcB);
      unsigned bAhi = (unsigned)__shfl((int)phi[2 * kk2], srcB);
      unsigned bBlo = (unsigned)__shfl((int)plo[2 * kk2 + 1], srcB);
      unsigned bBhi = (unsigned)__shfl((int)phi[2 * kk2 + 1], srcB);
      uint4v dws;
      dws[0] = hig ? aBlo : aAlo;
      dws[1] = hig ? aBhi : aAhi;
      dws[2] = hig ? bBlo : bAlo;
      dws[3] = hig ? bBhi : bAhi;
      short8 pbf = __builtin_bit_cast(short8, dws);
      __builtin_amdgcn_s_setprio(1);
#pragma unroll
      for (int d = 0; d < 8; ++d) {
        short8 vf = *(const short8*)&Vc[(16 * d + li) * 64 + ((((kk2 << 2) | gi)) ^ (li & 7)) * 8];
        o[d] = mfma16(vf, pbf, o[d]);
      }
      __builtin_amdgcn_s_setprio(0);
    }
    __builtin_amdgcn_s_barrier();                 // readers done -> buffer restageable
  }
#undef FSTAGE

  const float inv = 1.0f / lsum;
  const int b = bh >> 4, h = bh & 15;
  const size_t obase = ((size_t)b * SEQ + mrow) * DIM + h * HD;
#pragma unroll
  for (int d = 0; d < 8; ++d) {
    short4v st;
#pragma unroll
    for (int r = 0; r < 4; ++r) st[r] = f2bf(o[d][r] * inv);
    *(short4v*)&Og[obase + d * 16 + 4 * gi] = st;
  }
}

// ---------------------------------------------------------------- launcher
extern "C" void kernel_launch(void* const* d_in, const int* in_sizes, int n_in,
                              void* d_out, int out_size, void* d_ws, size_t ws_size,
                              hipStream_t stream) {
  (void)in_sizes; (void)n_in; (void)out_size;
  const float* x    = (const float*)d_in[0];
  const float* cosg = (const float*)d_in[1];
  const float* sing = (const float*)d_in[2];
  const float* wq   = (const float*)d_in[3];
  const float* wk   = (const float*)d_in[4];
  const float* wv   = (const float*)d_in[5];
  const float* wo   = (const float*)d_in[6];

  const size_t SZ = (size_t)MROWS * DIM * 2;      // 33,554,432 B
  char* ws = (char*)d_ws;
  short* xb  = (short*)ws;                        // region 0, later reused as attn-out O
  short* wqT = (short*)(ws + SZ);                 // wqT|wkT|wvT contiguous (BtAll)
  short* wkT = wqT + (size_t)DIM * DIM;
  short* wvT = wkT + (size_t)DIM * DIM;
  short* woT = wvT + (size_t)DIM * DIM;
  short *Qp, *Kp, *Vp;
  if (ws_size >= 5 * SZ) {
    Qp = (short*)(ws + 2 * SZ);
    Kp = (short*)(ws + 3 * SZ);
    Vp = (short*)(ws + 4 * SZ);
  } else {                                        // park Q,K in d_out (overwritten at the end)
    Qp = (short*)d_out;
    Kp = (short*)d_out + SZ / 2;
    Vp = (short*)(ws + 2 * SZ);
  }
  short* Ob = xb;                                 // alias: xb dead after QKV GEMM

  k_convert_x<<<8192, 256, 0, stream>>>(x, xb);
  k_transpose_w<<<dim3(64, 64, 4), dim3(32, 8), 0, stream>>>(wq, wk, wv, wo,
                                                             wqT, wkT, wvT, woT);
  k_gemm256<0><<<768, 512, 0, stream>>>(xb, wqT, cosg, sing, Qp, Kp, Vp, nullptr);
  k_flash<<<1024, 512, 0, stream>>>(Qp, Kp, Vp, Ob);
  k_gemm256<1><<<256, 512, 0, stream>>>(Ob, woT, nullptr, nullptr,
                                        nullptr, nullptr, nullptr, (float*)d_out);
}

// Round 16
// 411.518 us; speedup vs baseline: 1.0559x; 1.0559x over previous
//
#include <hip/hip_runtime.h>
#include <cstdint>
#include <cstddef>

#define DIM 2048
#define NHEADS 16
#define HD 128
#define BATCH 4
#define SEQ 2048
#define MROWS (BATCH*SEQ)   // 8192
#define NT 32               // K tiles (2048/64)
#define TSZ (256*64)        // one LDS tile in shorts (32 KiB)

typedef __attribute__((ext_vector_type(4))) float  f32x4;
typedef __attribute__((ext_vector_type(4))) float  float4v;
typedef __attribute__((ext_vector_type(8))) short  short8;
typedef __attribute__((ext_vector_type(4))) short  short4v;
typedef __attribute__((ext_vector_type(4))) unsigned uint4v;
typedef __attribute__((ext_vector_type(8))) __bf16 bf16x8;

// Q is pre-scaled by (1/sqrt(128)) * log2(e) so flash softmax runs in exp2 domain.
#define QSCALE 0.1275173772f

__device__ __forceinline__ unsigned f2bfbits(float f) {
  unsigned u = __builtin_bit_cast(unsigned, f);
  return (u + 0x7FFFu + ((u >> 16) & 1u)) >> 16;
}
__device__ __forceinline__ short f2bf(float f) { return (short)f2bfbits(f); }
__device__ __forceinline__ float bf2f(short s) {
  unsigned u = ((unsigned)(unsigned short)s) << 16;
  return __builtin_bit_cast(float, u);
}
__device__ __forceinline__ unsigned cvtpk_bf16(float lo, float hi) {
  unsigned r;
  asm("v_cvt_pk_bf16_f32 %0, %1, %2" : "=v"(r) : "v"(lo), "v"(hi));
  return r;
}
__device__ __forceinline__ f32x4 mfma16(short8 a, short8 b, f32x4 c) {
  return __builtin_amdgcn_mfma_f32_16x16x32_bf16(
      __builtin_bit_cast(bf16x8, a), __builtin_bit_cast(bf16x8, b), c, 0, 0, 0);
}
// async global->LDS, 16B per lane. LDS dest is wave-uniform base + lane*16.
__device__ __forceinline__ void gload16(const short* g, short* l) {
  __builtin_amdgcn_global_load_lds(
      (const __attribute__((address_space(1))) unsigned int*)g,
      (__attribute__((address_space(3))) unsigned int*)l, 16, 0, 0);
}

// ---------------------------------------------------------------- fused prep
// Blocks 0..16383: transpose W [K][N] f32 -> Wt [N][K] bf16 (z = id>>12 picks w).
// Blocks 16384..24575: convert x f32 -> bf16 (streaming).
// One launch so the LDS-bound transpose overlaps the pure-streaming convert.
__global__ __launch_bounds__(256) void k_prep(
    const float* __restrict__ x, short* __restrict__ xb,
    const float* __restrict__ w0, const float* __restrict__ w1,
    const float* __restrict__ w2, const float* __restrict__ w3,
    short* __restrict__ o0, short* __restrict__ o1,
    short* __restrict__ o2, short* __restrict__ o3) {
  __shared__ float tile[32][33];
  const int id = blockIdx.x, t = threadIdx.x;
  if (id < 16384) {
    const float* w; short* o;
    switch (id >> 12) {
      case 0: w = w0; o = o0; break;
      case 1: w = w1; o = o1; break;
      case 2: w = w2; o = o2; break;
      default: w = w3; o = o3; break;
    }
    const int rem = id & 4095;
    const int kb = (rem >> 6) * 32, nb = (rem & 63) * 32;
    const int tx = t & 31, ty = t >> 5;            // 32 x 8
#pragma unroll
    for (int i = 0; i < 4; ++i)
      tile[ty + 8 * i][tx] = w[(size_t)(kb + ty + 8 * i) * DIM + nb + tx];
    __syncthreads();
#pragma unroll
    for (int i = 0; i < 4; ++i)
      o[(size_t)(nb + ty + 8 * i) * DIM + kb + tx] = f2bf(tile[tx][ty + 8 * i]);
  } else {
    size_t i = ((size_t)(id - 16384) * 256 + t) * 8;
    float4v a = *(const float4v*)(x + i);
    float4v b = *(const float4v*)(x + i + 4);
    short8 o;
    o[0] = f2bf(a[0]); o[1] = f2bf(a[1]); o[2] = f2bf(a[2]); o[3] = f2bf(a[3]);
    o[4] = f2bf(b[0]); o[5] = f2bf(b[1]); o[6] = f2bf(b[2]); o[7] = f2bf(b[3]);
    *(short8*)(xb + i) = o;
  }
}

// ---------------------------------------------------------------- 256x256 8-wave GEMM
// (round-14 best: 224 us, MfmaUtil 40.5) m201-faithful 4-phase schedule, 9
// barriers/tile (top + pre/post-MFMA per phase). 512 thr = 8 waves (2M x 4N),
// wave tile 128x64, acc[8][4]. LDS: 2 x (A+B) 256x64 = 128 KiB, half-tile
// staging granularity. Per K-tile t (buf c=t&1):
//   ph1: read av(ih0,ks0)+bv0; stage A.H1(t+1)->c^1; [barrier; MFMA; barrier]
//   ph2: read av(ih0,ks1)+bv1; stage A.H2(t+1);      [barrier; MFMA; barrier]
//   ph3: read av(ih1,ks0); stage B.H1(t+2)->c;       [barrier; MFMA; barrier]
//   ph4: read av(ih1,ks1); stage B.H2(t+2);          [barrier; MFMA;
//        vmcnt(4) (A(t+1) landed, B(t+2) in flight); barrier]
// 24 ds_read_b128/wave/tile (reuse-minimal); reads issued pre-barrier so their
// latency is absorbed by the rendezvous; counted waits never drain mid-loop.
// LDS XOR swizzle both-sides: LDS[r][s] = G[r][s ^ (r&7)].
// MODE 0: fused QKV + RoPE (grid 768 flat, XCD remap); MODE 1: out proj (grid 256).
template<int MODE>
__global__ __launch_bounds__(512, 1) void k_gemm256(const short* __restrict__ A,
                                                    const short* __restrict__ BtAll,
                                                    const float* __restrict__ cosg,
                                                    const float* __restrict__ sing,
                                                    short* __restrict__ Qp,
                                                    short* __restrict__ Kp,
                                                    short* __restrict__ Vp,
                                                    float* __restrict__ Of) {
  __shared__ short As[2 * TSZ];
  __shared__ short Bs[2 * TSZ];
  const int t = threadIdx.x;
  const int lane = t & 63, wid = t >> 6;          // 8 waves
  const int wm = wid >> 2, wn = wid & 3;          // 2 x 4
  const int gi = lane >> 4, li = lane & 15;
  const int id = blockIdx.x;
  const int wg = MODE == 0 ? ((id & 7) * 96 + (id >> 3)) : ((id & 7) * 32 + (id >> 3));
  const int bm = wg & 31, bn = wg >> 5;
  const int m0 = bm * 256;
  const int which = MODE == 0 ? (bn >> 3) : 0;
  const int n0 = MODE == 0 ? ((bn & 7) * 256) : (bn * 256);
  const short* Bg = BtAll + (size_t)which * DIM * DIM;
  const short* Ag = A;

  const int lrow = lane >> 3;                     // 0..7
  const int lcol = ((lane & 7) ^ lrow) * 8;       // pre-swizzled source col (shorts)
  const int hh = wn >> 1, hf = wn & 1;            // MODE 0 col remap

  auto bcol = [&](int j) {
    if (MODE == 0) return hh * 128 + (j >> 1) * 64 + hf * 32 + (j & 1) * 16;
    return wn * 64 + j * 16;
  };

  auto stageA = [&](int h, int tile) {
    const int kk0 = tile * 64;
    short* d = As + (tile & 1) * TSZ;
#pragma unroll
    for (int u = 0; u < 2; ++u) {
      int rb = h * 128 + u * 64 + wid * 8;
      gload16(Ag + (size_t)(m0 + rb + lrow) * DIM + kk0 + lcol, d + rb * 64);
    }
  };
  auto stageB = [&](int h, int tile) {
    const int kk0 = tile * 64;
    short* d = Bs + (tile & 1) * TSZ;
#pragma unroll
    for (int u = 0; u < 2; ++u) {
      int rb = h * 128 + u * 64 + wid * 8;
      gload16(Bg + (size_t)(n0 + rb + lrow) * DIM + kk0 + lcol, d + rb * 64);
    }
  };

  f32x4 acc[8][4];
#pragma unroll
  for (int i = 0; i < 8; ++i)
#pragma unroll
    for (int j = 0; j < 4; ++j) acc[i][j] = (f32x4){0.f, 0.f, 0.f, 0.f};

#define READ_AV(IH, KS)                                                           \
  { const int sw = ((((KS) << 2) | gi) ^ (li & 7)) * 8;                           \
    _Pragma("unroll")                                                             \
    for (int i = 0; i < 4; ++i)                                                   \
      av[i] = *(const short8*)&Ab[(wm * 128 + ((IH) * 4 + i) * 16 + li) * 64 + sw]; }
#define READ_BV(DST, KS)                                                          \
  { const int sw = ((((KS) << 2) | gi) ^ (li & 7)) * 8;                           \
    _Pragma("unroll")                                                             \
    for (int j = 0; j < 4; ++j)                                                   \
      DST[j] = *(const short8*)&Bb[(bcol(j) + li) * 64 + sw]; }
#define PHASE_MFMA(IH, BV)                                                        \
  __builtin_amdgcn_s_barrier();                                                   \
  __builtin_amdgcn_s_setprio(1);                                                  \
  _Pragma("unroll")                                                               \
  for (int i = 0; i < 4; ++i)                                                     \
    _Pragma("unroll")                                                             \
    for (int j = 0; j < 4; ++j)                                                   \
      acc[(IH) * 4 + i][j] = mfma16(av[i], BV[j], acc[(IH) * 4 + i][j]);          \
  __builtin_amdgcn_s_setprio(0);

  // prologue (steady-state issue order: B(t) two tiles early, A(t) one early)
  stageB(0, 0); stageB(1, 0);
  stageA(0, 0); stageA(1, 0);
  stageB(0, 1); stageB(1, 1);
  asm volatile("s_waitcnt vmcnt(4)" ::: "memory");
  __builtin_amdgcn_s_barrier();

  for (int tt = 0; tt < NT; ++tt) {
    const short* Ab = As + (tt & 1) * TSZ;
    const short* Bb = Bs + (tt & 1) * TSZ;
    short8 av[4], bv0[4], bv1[4];

    // ph1: ih0 x ks0
    READ_AV(0, 0)
    READ_BV(bv0, 0)
    if (tt + 1 < NT) stageA(0, tt + 1);
    PHASE_MFMA(0, bv0)
    __builtin_amdgcn_s_barrier();

    // ph2: ih0 x ks1
    READ_AV(0, 1)
    READ_BV(bv1, 1)
    if (tt + 1 < NT) stageA(1, tt + 1);
    PHASE_MFMA(0, bv1)
    __builtin_amdgcn_s_barrier();

    // ph3: ih1 x ks0 (bv0 held in regs; B of t dead -> restage for t+2)
    READ_AV(1, 0)
    if (tt + 2 < NT) stageB(0, tt + 2);
    PHASE_MFMA(1, bv0)
    __builtin_amdgcn_s_barrier();

    // ph4: ih1 x ks1
    READ_AV(1, 1)
    if (tt + 2 < NT) stageB(1, tt + 2);
    PHASE_MFMA(1, bv1)
    if (tt + 2 < NT) asm volatile("s_waitcnt vmcnt(4)" ::: "memory");
    else             asm volatile("s_waitcnt vmcnt(0)" ::: "memory");
    __builtin_amdgcn_s_barrier();
  }
#undef READ_AV
#undef READ_BV
#undef PHASE_MFMA

  // ---------------- epilogue ----------------
  if (MODE == 1) {
#pragma unroll
    for (int i = 0; i < 8; ++i)
#pragma unroll
      for (int j = 0; j < 4; ++j)
#pragma unroll
        for (int r = 0; r < 4; ++r) {
          int gm = m0 + wm * 128 + i * 16 + gi * 4 + r;
          int gn = n0 + wn * 64 + j * 16 + li;
          Of[(size_t)gm * DIM + gn] = acc[i][j][r];
        }
    return;
  }
  const int h = 2 * (bn & 7) + hh;
  if (which == 2) {                               // V -> (B,H,D,S)
#pragma unroll
    for (int i = 0; i < 8; ++i)
#pragma unroll
      for (int j = 0; j < 4; ++j) {
        int gm0 = m0 + wm * 128 + i * 16 + gi * 4;
        int b = gm0 >> 11, s0 = gm0 & 2047;
        int d = (j >> 1) * 64 + hf * 32 + (j & 1) * 16 + li;
        short4v pk;
#pragma unroll
        for (int r = 0; r < 4; ++r) pk[r] = f2bf(acc[i][j][r]);
        *(short4v*)&Vp[((size_t)(b * NHEADS + h) * HD + d) * SEQ + s0] = pk;
      }
  } else {                                        // Q or K: rope + store (B,H,S,D)
    short* O = which ? Kp : Qp;
    const float qs = which ? 1.0f : QSCALE;
#pragma unroll
    for (int i = 0; i < 8; ++i)
#pragma unroll
      for (int j = 0; j < 2; ++j) {
        int dlo = hf * 32 + j * 16 + li;          // in [0,64)
#pragma unroll
        for (int r = 0; r < 4; ++r) {
          int gm = m0 + wm * 128 + i * 16 + gi * 4 + r;
          int b = gm >> 11, s = gm & 2047;
          float c = cosg[s * 64 + dlo], sn = sing[s * 64 + dlo];
          float a = acc[i][j][r], bb = acc[i][j + 2][r];
          size_t base = ((size_t)(b * NHEADS + h) * SEQ + s) * HD;
          O[base + dlo]      = f2bf((a * c - bb * sn) * qs);
          O[base + dlo + 64] = f2bf((bb * c + a * sn) * qs);
        }
      }
  }
}

// ---------------------------------------------------------------- causal flash attention
// Q (QSCALE'd, roped), K (roped): (B,H,S,D) bf16; V: (B,H,D,S) bf16; O: (B,S,H*D) bf16.
// 8 waves x 16 q-rows = 128 q-rows per block; each staged K/V tile feeds all 8 waves.
// Staging via gload_lds(16B) into linear LDS, XOR-swizzled both sides.
// Double-buffered, counted vmcnt(4). Grid 1024 with XCD bh-affinity + LPT.
__global__ __launch_bounds__(512) void k_flash(const short* __restrict__ Qg,
                                               const short* __restrict__ Kg,
                                               const short* __restrict__ Vg,
                                               short* __restrict__ Og) {
  __shared__ short Kl[2 * 64 * 128];
  __shared__ short Vl[2 * 128 * 64];
  const int t = threadIdx.x, lane = t & 63, wid = t >> 6;   // 8 waves
  const int gi = lane >> 4, li = lane & 15;
  const int id = blockIdx.x;
  const int ip = 15 - (id >> 6);                  // q-tile (128 rows), heavy-first
  const int bh = (id & 7) * 8 + ((id >> 3) & 7);  // XCD bh-affinity
  const int q0 = ip * 128;
  const short* Qb = Qg + (size_t)bh * SEQ * HD;
  const short* Kb = Kg + (size_t)bh * SEQ * HD;
  const short* Vb = Vg + (size_t)bh * HD * SEQ;
  const int mrow = q0 + wid * 16 + li;            // this lane's q row
  const int nt = 2 * ip + 2;

  short8 qb[4];
#pragma unroll
  for (int kk = 0; kk < 4; ++kk)
    qb[kk] = *(const short8*)(Qb + (size_t)mrow * HD + kk * 32 + 8 * gi);

  f32x4 o[8];
#pragma unroll
  for (int d = 0; d < 8; ++d) o[d] = (f32x4){0.f, 0.f, 0.f, 0.f};
  float mx = -1e30f, lsum = 0.f;
  const int srcA = li | ((lane & 16) << 1);       // (m, 2*(g&1))
  const int srcB = srcA + 16;
  const bool hig = (lane & 32) != 0;

#define FSTAGE(tt, buf)                                                           \
  {                                                                               \
    const int kk0 = (tt) * 64;                                                    \
    short* kl = Kl + (buf) * 8192;                                                \
    short* vl = Vl + (buf) * 8192;                                                \
    _Pragma("unroll")                                                             \
    for (int u = 0; u < 2; ++u) {                                                 \
      int w = wid * 2 + u;                                                        \
      { int row = w * 4 + (lane >> 4); int sl = (lane & 15) ^ (row & 15);         \
        gload16(Kb + (size_t)(kk0 + row) * HD + sl * 8, kl + w * 512); }          \
      { int row = w * 8 + (lane >> 3); int sl = (lane & 7) ^ (row & 7);           \
        gload16(Vb + (size_t)row * SEQ + kk0 + sl * 8, vl + w * 512); }           \
    }                                                                             \
  }

  FSTAGE(0, 0)

  for (int tt = 0; tt < nt; ++tt) {
    const int k0 = tt * 64;
    if (tt + 1 < nt) {
      FSTAGE(tt + 1, (tt + 1) & 1)
      asm volatile("s_waitcnt vmcnt(4)" ::: "memory");
    } else {
      asm volatile("s_waitcnt vmcnt(0)" ::: "memory");
    }
    __builtin_amdgcn_s_barrier();                 // tile tt staged everywhere
    const short* Kc = Kl + (tt & 1) * 8192;
    const short* Vc = Vl + (tt & 1) * 8192;

    f32x4 sacc[4];
#pragma unroll
    for (int af = 0; af < 4; ++af) sacc[af] = (f32x4){0.f, 0.f, 0.f, 0.f};
    __builtin_amdgcn_s_setprio(1);
#pragma unroll
    for (int kk = 0; kk < 4; ++kk)
#pragma unroll
      for (int af = 0; af < 4; ++af) {
        short8 kf = *(const short8*)&Kc[(16 * af + li) * 128 + (((kk << 2) | gi) ^ li) * 8];
        sacc[af] = mfma16(kf, qb[kk], sacc[af]);
      }
    __builtin_amdgcn_s_setprio(0);

    float p[4][4];
    float pmax = -1e30f;
    const bool mask = (k0 + 63 > mrow);
#pragma unroll
    for (int af = 0; af < 4; ++af)
#pragma unroll
      for (int r = 0; r < 4; ++r) {
        float v = sacc[af][r];                    // already scaled (Q pre-scale)
        if (mask && (k0 + 16 * af + 4 * gi + r > mrow)) v = -1e30f;
        p[af][r] = v;
        pmax = fmaxf(pmax, v);
      }
    pmax = fmaxf(pmax, __shfl_xor(pmax, 16));
    pmax = fmaxf(pmax, __shfl_xor(pmax, 32));
    if (!__all(pmax <= mx + 11.54f)) {            // defer-max: rescale only on real growth
      float mnew = fmaxf(mx, pmax);
      float alpha = __builtin_amdgcn_exp2f(mx - mnew);
      lsum *= alpha;
      mx = mnew;
#pragma unroll
      for (int d = 0; d < 8; ++d) o[d] *= alpha;
    }
    float psum = 0.f;
#pragma unroll
    for (int af = 0; af < 4; ++af)
#pragma unroll
      for (int r = 0; r < 4; ++r) {
        float e = __builtin_amdgcn_exp2f(p[af][r] - mx);
        p[af][r] = e;
        psum += e;
      }
    psum += __shfl_xor(psum, 16);
    psum += __shfl_xor(psum, 32);
    lsum += psum;

    unsigned plo[4], phi[4];
#pragma unroll
    for (int af = 0; af < 4; ++af) {
      plo[af] = cvtpk_bf16(p[af][0], p[af][1]);
      phi[af] = cvtpk_bf16(p[af][2], p[af][3]);
    }
#pragma unroll
    for (int kk2 = 0; kk2 < 2; ++kk2) {
      unsigned aAlo = (unsigned)__shfl((int)plo[2 * kk2], srcA);
      unsigned aAhi = (unsigned)__shfl((int)phi[2 * kk2], srcA);
      unsigned aBlo = (unsigned)__shfl((int)plo[2 * kk2 + 1], srcA);
      unsigned aBhi = (unsigned)__shfl((int)phi[2 * kk2 + 1], srcA);
      unsigned bAlo = (unsigned)__shfl((int)plo[2 * kk2], srcB);
      unsigned bAhi = (unsigned)__shfl((int)phi[2 * kk2], srcB);
      unsigned bBlo = (unsigned)__shfl((int)plo[2 * kk2 + 1], srcB);
      unsigned bBhi = (unsigned)__shfl((int)phi[2 * kk2 + 1], srcB);
      uint4v dws;
      dws[0] = hig ? aBlo : aAlo;
      dws[1] = hig ? aBhi : aAhi;
      dws[2] = hig ? bBlo : bAlo;
      dws[3] = hig ? bBhi : bAhi;
      short8 pbf = __builtin_bit_cast(short8, dws);
      __builtin_amdgcn_s_setprio(1);
#pragma unroll
      for (int d = 0; d < 8; ++d) {
        short8 vf = *(const short8*)&Vc[(16 * d + li) * 64 + ((((kk2 << 2) | gi)) ^ (li & 7)) * 8];
        o[d] = mfma16(vf, pbf, o[d]);
      }
      __builtin_amdgcn_s_setprio(0);
    }
    __builtin_amdgcn_s_barrier();                 // readers done -> buffer restageable
  }
#undef FSTAGE

  const float inv = 1.0f / lsum;
  const int b = bh >> 4, h = bh & 15;
  const size_t obase = ((size_t)b * SEQ + mrow) * DIM + h * HD;
#pragma unroll
  for (int d = 0; d < 8; ++d) {
    short4v st;
#pragma unroll
    for (int r = 0; r < 4; ++r) st[r] = f2bf(o[d][r] * inv);
    *(short4v*)&Og[obase + d * 16 + 4 * gi] = st;
  }
}

// ---------------------------------------------------------------- launcher
extern "C" void kernel_launch(void* const* d_in, const int* in_sizes, int n_in,
                              void* d_out, int out_size, void* d_ws, size_t ws_size,
                              hipStream_t stream) {
  (void)in_sizes; (void)n_in; (void)out_size;
  const float* x    = (const float*)d_in[0];
  const float* cosg = (const float*)d_in[1];
  const float* sing = (const float*)d_in[2];
  const float* wq   = (const float*)d_in[3];
  const float* wk   = (const float*)d_in[4];
  const float* wv   = (const float*)d_in[5];
  const float* wo   = (const float*)d_in[6];

  const size_t SZ = (size_t)MROWS * DIM * 2;      // 33,554,432 B
  char* ws = (char*)d_ws;
  short* xb  = (short*)ws;                        // region 0, later reused as attn-out O
  short* wqT = (short*)(ws + SZ);                 // wqT|wkT|wvT contiguous (BtAll)
  short* wkT = wqT + (size_t)DIM * DIM;
  short* wvT = wkT + (size_t)DIM * DIM;
  short* woT = wvT + (size_t)DIM * DIM;
  short *Qp, *Kp, *Vp;
  if (ws_size >= 5 * SZ) {
    Qp = (short*)(ws + 2 * SZ);
    Kp = (short*)(ws + 3 * SZ);
    Vp = (short*)(ws + 4 * SZ);
  } else {                                        // park Q,K in d_out (overwritten at the end)
    Qp = (short*)d_out;
    Kp = (short*)d_out + SZ / 2;
    Vp = (short*)(ws + 2 * SZ);
  }
  short* Ob = xb;                                 // alias: xb dead after QKV GEMM

  k_prep<<<24576, 256, 0, stream>>>(x, xb, wq, wk, wv, wo, wqT, wkT, wvT, woT);
  k_gemm256<0><<<768, 512, 0, stream>>>(xb, wqT, cosg, sing, Qp, Kp, Vp, nullptr);
  k_flash<<<1024, 512, 0, stream>>>(Qp, Kp, Vp, Ob);
  k_gemm256<1><<<256, 512, 0, stream>>>(Ob, woT, nullptr, nullptr,
                                        nullptr, nullptr, nullptr, (float*)d_out);
}

// Round 17
// 407.967 us; speedup vs baseline: 1.0651x; 1.0087x over previous
//
#include <hip/hip_runtime.h>
#include <cstdint>
#include <cstddef>

#define DIM 2048
#define NHEADS 16
#define HD 128
#define BATCH 4
#define SEQ 2048
#define MROWS (BATCH*SEQ)   // 8192
#define NT 32               // K tiles (2048/64)
#define TSZ (256*64)        // one LDS tile in shorts (32 KiB)

typedef __attribute__((ext_vector_type(4))) float  f32x4;
typedef __attribute__((ext_vector_type(4))) float  float4v;
typedef __attribute__((ext_vector_type(8))) short  short8;
typedef __attribute__((ext_vector_type(4))) short  short4v;
typedef __attribute__((ext_vector_type(4))) unsigned uint4v;
typedef __attribute__((ext_vector_type(8))) __bf16 bf16x8;

// Q is pre-scaled by (1/sqrt(128)) * log2(e) so flash softmax runs in exp2 domain.
#define QSCALE 0.1275173772f

__device__ __forceinline__ unsigned f2bfbits(float f) {
  unsigned u = __builtin_bit_cast(unsigned, f);
  return (u + 0x7FFFu + ((u >> 16) & 1u)) >> 16;
}
__device__ __forceinline__ short f2bf(float f) { return (short)f2bfbits(f); }
__device__ __forceinline__ float bf2f(short s) {
  unsigned u = ((unsigned)(unsigned short)s) << 16;
  return __builtin_bit_cast(float, u);
}
__device__ __forceinline__ unsigned cvtpk_bf16(float lo, float hi) {
  unsigned r;
  asm("v_cvt_pk_bf16_f32 %0, %1, %2" : "=v"(r) : "v"(lo), "v"(hi));
  return r;
}
__device__ __forceinline__ f32x4 mfma16(short8 a, short8 b, f32x4 c) {
  return __builtin_amdgcn_mfma_f32_16x16x32_bf16(
      __builtin_bit_cast(bf16x8, a), __builtin_bit_cast(bf16x8, b), c, 0, 0, 0);
}
// async global->LDS, 16B per lane. LDS dest is wave-uniform base + lane*16.
__device__ __forceinline__ void gload16(const short* g, short* l) {
  __builtin_amdgcn_global_load_lds(
      (const __attribute__((address_space(1))) unsigned int*)g,
      (__attribute__((address_space(3))) unsigned int*)l, 16, 0, 0);
}

// ---------------------------------------------------------------- fused prep
// Blocks 0..16383: transpose W [K][N] f32 -> Wt [N][K] bf16 (z = id>>12 picks w).
// Blocks 16384..24575: convert x f32 -> bf16 (streaming).
// One launch so the LDS-bound transpose overlaps the pure-streaming convert.
__global__ __launch_bounds__(256) void k_prep(
    const float* __restrict__ x, short* __restrict__ xb,
    const float* __restrict__ w0, const float* __restrict__ w1,
    const float* __restrict__ w2, const float* __restrict__ w3,
    short* __restrict__ o0, short* __restrict__ o1,
    short* __restrict__ o2, short* __restrict__ o3) {
  __shared__ float tile[32][33];
  const int id = blockIdx.x, t = threadIdx.x;
  if (id < 16384) {
    const float* w; short* o;
    switch (id >> 12) {
      case 0: w = w0; o = o0; break;
      case 1: w = w1; o = o1; break;
      case 2: w = w2; o = o2; break;
      default: w = w3; o = o3; break;
    }
    const int rem = id & 4095;
    const int kb = (rem >> 6) * 32, nb = (rem & 63) * 32;
    const int tx = t & 31, ty = t >> 5;            // 32 x 8
#pragma unroll
    for (int i = 0; i < 4; ++i)
      tile[ty + 8 * i][tx] = w[(size_t)(kb + ty + 8 * i) * DIM + nb + tx];
    __syncthreads();
#pragma unroll
    for (int i = 0; i < 4; ++i)
      o[(size_t)(nb + ty + 8 * i) * DIM + kb + tx] = f2bf(tile[tx][ty + 8 * i]);
  } else {
    size_t i = ((size_t)(id - 16384) * 256 + t) * 8;
    float4v a = *(const float4v*)(x + i);
    float4v b = *(const float4v*)(x + i + 4);
    short8 o;
    o[0] = f2bf(a[0]); o[1] = f2bf(a[1]); o[2] = f2bf(a[2]); o[3] = f2bf(a[3]);
    o[4] = f2bf(b[0]); o[5] = f2bf(b[1]); o[6] = f2bf(b[2]); o[7] = f2bf(b[3]);
    *(short8*)(xb + i) = o;
  }
}

// ---------------------------------------------------------------- 256x256 8-wave GEMM
// (measured optimum: ~224-231 us, MfmaUtil ~40) m201-style 4-phase schedule, 9
// barriers/tile (top + pre/post-MFMA per phase). 512 thr = 8 waves (2M x 4N),
// wave tile 128x64, acc[8][4]. LDS: 2 x (A+B) 256x64 = 128 KiB, half-tile
// staging granularity. Per K-tile t (buf c=t&1):
//   ph1: read av(ih0,ks0)+bv0; stage A.H1(t+1)->c^1; [barrier; MFMA; barrier]
//   ph2: read av(ih0,ks1)+bv1; stage A.H2(t+1);      [barrier; MFMA; barrier]
//   ph3: read av(ih1,ks0); stage B.H1(t+2)->c;       [barrier; MFMA; barrier]
//   ph4: read av(ih1,ks1); stage B.H2(t+2);          [barrier; MFMA;
//        vmcnt(4) (A(t+1) landed, B(t+2) in flight); barrier]
// 24 ds_read_b128/wave/tile (reuse-minimal); reads issued pre-barrier so their
// latency is absorbed by the rendezvous; counted waits never drain mid-loop.
// LDS XOR swizzle both-sides: LDS[r][s] = G[r][s ^ (r&7)].
// MODE 0: fused QKV + RoPE (grid 768 flat, XCD remap); MODE 1: out proj (grid 256).
template<int MODE>
__global__ __launch_bounds__(512, 1) void k_gemm256(const short* __restrict__ A,
                                                    const short* __restrict__ BtAll,
                                                    const float* __restrict__ cosg,
                                                    const float* __restrict__ sing,
                                                    short* __restrict__ Qp,
                                                    short* __restrict__ Kp,
                                                    short* __restrict__ Vp,
                                                    float* __restrict__ Of) {
  __shared__ short As[2 * TSZ];
  __shared__ short Bs[2 * TSZ];
  const int t = threadIdx.x;
  const int lane = t & 63, wid = t >> 6;          // 8 waves
  const int wm = wid >> 2, wn = wid & 3;          // 2 x 4
  const int gi = lane >> 4, li = lane & 15;
  const int id = blockIdx.x;
  const int wg = MODE == 0 ? ((id & 7) * 96 + (id >> 3)) : ((id & 7) * 32 + (id >> 3));
  const int bm = wg & 31, bn = wg >> 5;
  const int m0 = bm * 256;
  const int which = MODE == 0 ? (bn >> 3) : 0;
  const int n0 = MODE == 0 ? ((bn & 7) * 256) : (bn * 256);
  const short* Bg = BtAll + (size_t)which * DIM * DIM;
  const short* Ag = A;

  const int lrow = lane >> 3;                     // 0..7
  const int lcol = ((lane & 7) ^ lrow) * 8;       // pre-swizzled source col (shorts)
  const int hh = wn >> 1, hf = wn & 1;            // MODE 0 col remap

  auto bcol = [&](int j) {
    if (MODE == 0) return hh * 128 + (j >> 1) * 64 + hf * 32 + (j & 1) * 16;
    return wn * 64 + j * 16;
  };

  auto stageA = [&](int h, int tile) {
    const int kk0 = tile * 64;
    short* d = As + (tile & 1) * TSZ;
#pragma unroll
    for (int u = 0; u < 2; ++u) {
      int rb = h * 128 + u * 64 + wid * 8;
      gload16(Ag + (size_t)(m0 + rb + lrow) * DIM + kk0 + lcol, d + rb * 64);
    }
  };
  auto stageB = [&](int h, int tile) {
    const int kk0 = tile * 64;
    short* d = Bs + (tile & 1) * TSZ;
#pragma unroll
    for (int u = 0; u < 2; ++u) {
      int rb = h * 128 + u * 64 + wid * 8;
      gload16(Bg + (size_t)(n0 + rb + lrow) * DIM + kk0 + lcol, d + rb * 64);
    }
  };

  f32x4 acc[8][4];
#pragma unroll
  for (int i = 0; i < 8; ++i)
#pragma unroll
    for (int j = 0; j < 4; ++j) acc[i][j] = (f32x4){0.f, 0.f, 0.f, 0.f};

#define READ_AV(IH, KS)                                                           \
  { const int sw = ((((KS) << 2) | gi) ^ (li & 7)) * 8;                           \
    _Pragma("unroll")                                                             \
    for (int i = 0; i < 4; ++i)                                                   \
      av[i] = *(const short8*)&Ab[(wm * 128 + ((IH) * 4 + i) * 16 + li) * 64 + sw]; }
#define READ_BV(DST, KS)                                                          \
  { const int sw = ((((KS) << 2) | gi) ^ (li & 7)) * 8;                           \
    _Pragma("unroll")                                                             \
    for (int j = 0; j < 4; ++j)                                                   \
      DST[j] = *(const short8*)&Bb[(bcol(j) + li) * 64 + sw]; }
#define PHASE_MFMA(IH, BV)                                                        \
  __builtin_amdgcn_s_barrier();                                                   \
  __builtin_amdgcn_s_setprio(1);                                                  \
  _Pragma("unroll")                                                               \
  for (int i = 0; i < 4; ++i)                                                     \
    _Pragma("unroll")                                                             \
    for (int j = 0; j < 4; ++j)                                                   \
      acc[(IH) * 4 + i][j] = mfma16(av[i], BV[j], acc[(IH) * 4 + i][j]);          \
  __builtin_amdgcn_s_setprio(0);

  // prologue (steady-state issue order: B(t) two tiles early, A(t) one early)
  stageB(0, 0); stageB(1, 0);
  stageA(0, 0); stageA(1, 0);
  stageB(0, 1); stageB(1, 1);
  asm volatile("s_waitcnt vmcnt(4)" ::: "memory");
  __builtin_amdgcn_s_barrier();

  for (int tt = 0; tt < NT; ++tt) {
    const short* Ab = As + (tt & 1) * TSZ;
    const short* Bb = Bs + (tt & 1) * TSZ;
    short8 av[4], bv0[4], bv1[4];

    // ph1: ih0 x ks0
    READ_AV(0, 0)
    READ_BV(bv0, 0)
    if (tt + 1 < NT) stageA(0, tt + 1);
    PHASE_MFMA(0, bv0)
    __builtin_amdgcn_s_barrier();

    // ph2: ih0 x ks1
    READ_AV(0, 1)
    READ_BV(bv1, 1)
    if (tt + 1 < NT) stageA(1, tt + 1);
    PHASE_MFMA(0, bv1)
    __builtin_amdgcn_s_barrier();

    // ph3: ih1 x ks0 (bv0 held in regs; B of t dead -> restage for t+2)
    READ_AV(1, 0)
    if (tt + 2 < NT) stageB(0, tt + 2);
    PHASE_MFMA(1, bv0)
    __builtin_amdgcn_s_barrier();

    // ph4: ih1 x ks1
    READ_AV(1, 1)
    if (tt + 2 < NT) stageB(1, tt + 2);
    PHASE_MFMA(1, bv1)
    if (tt + 2 < NT) asm volatile("s_waitcnt vmcnt(4)" ::: "memory");
    else             asm volatile("s_waitcnt vmcnt(0)" ::: "memory");
    __builtin_amdgcn_s_barrier();
  }
#undef READ_AV
#undef READ_BV
#undef PHASE_MFMA

  // ---------------- epilogue ----------------
  if (MODE == 1) {
#pragma unroll
    for (int i = 0; i < 8; ++i)
#pragma unroll
      for (int j = 0; j < 4; ++j)
#pragma unroll
        for (int r = 0; r < 4; ++r) {
          int gm = m0 + wm * 128 + i * 16 + gi * 4 + r;
          int gn = n0 + wn * 64 + j * 16 + li;
          Of[(size_t)gm * DIM + gn] = acc[i][j][r];
        }
    return;
  }
  const int h = 2 * (bn & 7) + hh;
  if (which == 2) {                               // V -> (B,H,D,S)
#pragma unroll
    for (int i = 0; i < 8; ++i)
#pragma unroll
      for (int j = 0; j < 4; ++j) {
        int gm0 = m0 + wm * 128 + i * 16 + gi * 4;
        int b = gm0 >> 11, s0 = gm0 & 2047;
        int d = (j >> 1) * 64 + hf * 32 + (j & 1) * 16 + li;
        short4v pk;
#pragma unroll
        for (int r = 0; r < 4; ++r) pk[r] = f2bf(acc[i][j][r]);
        *(short4v*)&Vp[((size_t)(b * NHEADS + h) * HD + d) * SEQ + s0] = pk;
      }
  } else {                                        // Q or K: rope + store (B,H,S,D)
    short* O = which ? Kp : Qp;
    const float qs = which ? 1.0f : QSCALE;
#pragma unroll
    for (int i = 0; i < 8; ++i)
#pragma unroll
      for (int j = 0; j < 2; ++j) {
        int dlo = hf * 32 + j * 16 + li;          // in [0,64)
#pragma unroll
        for (int r = 0; r < 4; ++r) {
          int gm = m0 + wm * 128 + i * 16 + gi * 4 + r;
          int b = gm >> 11, s = gm & 2047;
          float c = cosg[s * 64 + dlo], sn = sing[s * 64 + dlo];
          float a = acc[i][j][r], bb = acc[i][j + 2][r];
          size_t base = ((size_t)(b * NHEADS + h) * SEQ + s) * HD;
          O[base + dlo]      = f2bf((a * c - bb * sn) * qs);
          O[base + dlo + 64] = f2bf((bb * c + a * sn) * qs);
        }
      }
  }
}

// ---------------------------------------------------------------- causal flash attention
// Q (QSCALE'd, roped), K (roped): (B,H,S,D) bf16; V: (B,H,D,S) bf16; O: (B,S,H*D) bf16.
// 8 waves x 16 q-rows = 128 q-rows per block; each staged K/V tile feeds all 8 waves.
// Staging via gload_lds(16B) into linear LDS, XOR-swizzled both sides.
// Double-buffered, counted vmcnt(4). Grid 1024 with XCD bh-affinity + LPT.
__global__ __launch_bounds__(512) void k_flash(const short* __restrict__ Qg,
                                               const short* __restrict__ Kg,
                                               const short* __restrict__ Vg,
                                               short* __restrict__ Og) {
  __shared__ short Kl[2 * 64 * 128];
  __shared__ short Vl[2 * 128 * 64];
  const int t = threadIdx.x, lane = t & 63, wid = t >> 6;   // 8 waves
  const int gi = lane >> 4, li = lane & 15;
  const int id = blockIdx.x;
  const int ip = 15 - (id >> 6);                  // q-tile (128 rows), heavy-first
  const int bh = (id & 7) * 8 + ((id >> 3) & 7);  // XCD bh-affinity
  const int q0 = ip * 128;
  const short* Qb = Qg + (size_t)bh * SEQ * HD;
  const short* Kb = Kg + (size_t)bh * SEQ * HD;
  const short* Vb = Vg + (size_t)bh * HD * SEQ;
  const int mrow = q0 + wid * 16 + li;            // this lane's q row
  const int nt = 2 * ip + 2;

  short8 qb[4];
#pragma unroll
  for (int kk = 0; kk < 4; ++kk)
    qb[kk] = *(const short8*)(Qb + (size_t)mrow * HD + kk * 32 + 8 * gi);

  f32x4 o[8];
#pragma unroll
  for (int d = 0; d < 8; ++d) o[d] = (f32x4){0.f, 0.f, 0.f, 0.f};
  float mx = -1e30f, lsum = 0.f;
  const int srcA = li | ((lane & 16) << 1);       // (m, 2*(g&1))
  const int srcB = srcA + 16;
  const bool hig = (lane & 32) != 0;

#define FSTAGE(tt, buf)                                                           \
  {                                                                               \
    const int kk0 = (tt) * 64;                                                    \
    short* kl = Kl + (buf) * 8192;                                                \
    short* vl = Vl + (buf) * 8192;                                                \
    _Pragma("unroll")                                                             \
    for (int u = 0; u < 2; ++u) {                                                 \
      int w = wid * 2 + u;                                                        \
      { int row = w * 4 + (lane >> 4); int sl = (lane & 15) ^ (row & 15);         \
        gload16(Kb + (size_t)(kk0 + row) * HD + sl * 8, kl + w * 512); }          \
      { int row = w * 8 + (lane >> 3); int sl = (lane & 7) ^ (row & 7);           \
        gload16(Vb + (size_t)row * SEQ + kk0 + sl * 8, vl + w * 512); }           \
    }                                                                             \
  }

  FSTAGE(0, 0)

  for (int tt = 0; tt < nt; ++tt) {
    const int k0 = tt * 64;
    if (tt + 1 < nt) {
      FSTAGE(tt + 1, (tt + 1) & 1)
      asm volatile("s_waitcnt vmcnt(4)" ::: "memory");
    } else {
      asm volatile("s_waitcnt vmcnt(0)" ::: "memory");
    }
    __builtin_amdgcn_s_barrier();                 // tile tt staged everywhere
    const short* Kc = Kl + (tt & 1) * 8192;
    const short* Vc = Vl + (tt & 1) * 8192;

    f32x4 sacc[4];
#pragma unroll
    for (int af = 0; af < 4; ++af) sacc[af] = (f32x4){0.f, 0.f, 0.f, 0.f};
    __builtin_amdgcn_s_setprio(1);
#pragma unroll
    for (int kk = 0; kk < 4; ++kk)
#pragma unroll
      for (int af = 0; af < 4; ++af) {
        short8 kf = *(const short8*)&Kc[(16 * af + li) * 128 + (((kk << 2) | gi) ^ li) * 8];
        sacc[af] = mfma16(kf, qb[kk], sacc[af]);
      }
    __builtin_amdgcn_s_setprio(0);

    float p[4][4];
    float pmax = -1e30f;
    const bool mask = (k0 + 63 > mrow);
#pragma unroll
    for (int af = 0; af < 4; ++af)
#pragma unroll
      for (int r = 0; r < 4; ++r) {
        float v = sacc[af][r];                    // already scaled (Q pre-scale)
        if (mask && (k0 + 16 * af + 4 * gi + r > mrow)) v = -1e30f;
        p[af][r] = v;
        pmax = fmaxf(pmax, v);
      }
    pmax = fmaxf(pmax, __shfl_xor(pmax, 16));
    pmax = fmaxf(pmax, __shfl_xor(pmax, 32));
    if (!__all(pmax <= mx + 11.54f)) {            // defer-max: rescale only on real growth
      float mnew = fmaxf(mx, pmax);
      float alpha = __builtin_amdgcn_exp2f(mx - mnew);
      lsum *= alpha;
      mx = mnew;
#pragma unroll
      for (int d = 0; d < 8; ++d) o[d] *= alpha;
    }
    float psum = 0.f;
#pragma unroll
    for (int af = 0; af < 4; ++af)
#pragma unroll
      for (int r = 0; r < 4; ++r) {
        float e = __builtin_amdgcn_exp2f(p[af][r] - mx);
        p[af][r] = e;
        psum += e;
      }
    psum += __shfl_xor(psum, 16);
    psum += __shfl_xor(psum, 32);
    lsum += psum;

    unsigned plo[4], phi[4];
#pragma unroll
    for (int af = 0; af < 4; ++af) {
      plo[af] = cvtpk_bf16(p[af][0], p[af][1]);
      phi[af] = cvtpk_bf16(p[af][2], p[af][3]);
    }
#pragma unroll
    for (int kk2 = 0; kk2 < 2; ++kk2) {
      unsigned aAlo = (unsigned)__shfl((int)plo[2 * kk2], srcA);
      unsigned aAhi = (unsigned)__shfl((int)phi[2 * kk2], srcA);
      unsigned aBlo = (unsigned)__shfl((int)plo[2 * kk2 + 1], srcA);
      unsigned aBhi = (unsigned)__shfl((int)phi[2 * kk2 + 1], srcA);
      unsigned bAlo = (unsigned)__shfl((int)plo[2 * kk2], srcB);
      unsigned bAhi = (unsigned)__shfl((int)phi[2 * kk2], srcB);
      unsigned bBlo = (unsigned)__shfl((int)plo[2 * kk2 + 1], srcB);
      unsigned bBhi = (unsigned)__shfl((int)phi[2 * kk2 + 1], srcB);
      uint4v dws;
      dws[0] = hig ? aBlo : aAlo;
      dws[1] = hig ? aBhi : aAhi;
      dws[2] = hig ? bBlo : bAlo;
      dws[3] = hig ? bBhi : bAhi;
      short8 pbf = __builtin_bit_cast(short8, dws);
      __builtin_amdgcn_s_setprio(1);
#pragma unroll
      for (int d = 0; d < 8; ++d) {
        short8 vf = *(const short8*)&Vc[(16 * d + li) * 64 + ((((kk2 << 2) | gi)) ^ (li & 7)) * 8];
        o[d] = mfma16(vf, pbf, o[d]);
      }
      __builtin_amdgcn_s_setprio(0);
    }
    __builtin_amdgcn_s_barrier();                 // readers done -> buffer restageable
  }
#undef FSTAGE

  const float inv = 1.0f / lsum;
  const int b = bh >> 4, h = bh & 15;
  const size_t obase = ((size_t)b * SEQ + mrow) * DIM + h * HD;
#pragma unroll
  for (int d = 0; d < 8; ++d) {
    short4v st;
#pragma unroll
    for (int r = 0; r < 4; ++r) st[r] = f2bf(o[d][r] * inv);
    *(short4v*)&Og[obase + d * 16 + 4 * gi] = st;
  }
}

// ---------------------------------------------------------------- launcher
extern "C" void kernel_launch(void* const* d_in, const int* in_sizes, int n_in,
                              void* d_out, int out_size, void* d_ws, size_t ws_size,
                              hipStream_t stream) {
  (void)in_sizes; (void)n_in; (void)out_size;
  const float* x    = (const float*)d_in[0];
  const float* cosg = (const float*)d_in[1];
  const float* sing = (const float*)d_in[2];
  const float* wq   = (const float*)d_in[3];
  const float* wk   = (const float*)d_in[4];
  const float* wv   = (const float*)d_in[5];
  const float* wo   = (const float*)d_in[6];

  const size_t SZ = (size_t)MROWS * DIM * 2;      // 33,554,432 B
  char* ws = (char*)d_ws;
  short* xb  = (short*)ws;                        // region 0, later reused as attn-out O
  short* wqT = (short*)(ws + SZ);                 // wqT|wkT|wvT contiguous (BtAll)
  short* wkT = wqT + (size_t)DIM * DIM;
  short* wvT = wkT + (size_t)DIM * DIM;
  short* woT = wvT + (size_t)DIM * DIM;
  short *Qp, *Kp, *Vp;
  if (ws_size >= 5 * SZ) {
    Qp = (short*)(ws + 2 * SZ);
    Kp = (short*)(ws + 3 * SZ);
    Vp = (short*)(ws + 4 * SZ);
  } else {                                        // park Q,K in d_out (overwritten at the end)
    Qp = (short*)d_out;
    Kp = (short*)d_out + SZ / 2;
    Vp = (short*)(ws + 2 * SZ);
  }
  short* Ob = xb;                                 // alias: xb dead after QKV GEMM

  k_prep<<<24576, 256, 0, stream>>>(x, xb, wq, wk, wv, wo, wqT, wkT, wvT, woT);
  k_gemm256<0><<<768, 512, 0, stream>>>(xb, wqT, cosg, sing, Qp, Kp, Vp, nullptr);
  k_flash<<<1024, 512, 0, stream>>>(Qp, Kp, Vp, Ob);
  k_gemm256<1><<<256, 512, 0, stream>>>(Ob, woT, nullptr, nullptr,
                                        nullptr, nullptr, nullptr, (float*)d_out);
}